// Round 12
// baseline (354.135 us; speedup 1.0000x reference)
//
#include <hip/hip_runtime.h>
#include <hip/hip_bf16.h>

// Problem constants (fixed by the reference).
#define N_NODES 30000
#define N_EDGES 240000
#define NB      64                  // batches
#define FDIM    64                  // F
#define NH      4                   // heads
#define HF      256                 // H*F
#define E2      (N_EDGES + N_NODES) // edges + self-loops
#define GCOLS   832                 // F*(1+H*T)
#define BOTD    256
#define DEGCAP  64                  // max in-degree bucket (Poisson(9): P(>63) ~ 1e-30)
#define PSPLIT  16                  // pool parallelism: blocks per batch
#define FSPLIT  8                   // final head split-K (832 = 8*104)

typedef __hip_bfloat16 bf16;
typedef __attribute__((ext_vector_type(8))) short short8;
typedef __attribute__((ext_vector_type(4))) float f32x4;

#define LDA 40   // LDS stride in halves: 80B = 16B-aligned, 2-way banking (free)

__device__ __forceinline__ float b2f(bf16 v) { return __bfloat162float(v); }

// ---- 0. mega-prologue: four independent kernels in one dispatch.
//      sections: [enc | fill_adj | boff | wconv]; branch is block-uniform. ----
#define ENC_B   7500                           // N*64/256
#define ADJ_B   1055                           // ceil(E2/256)
#define BOFF_B  118                            // ceil(N/256)
#define WT0 (HF * FDIM)
#define WT1 (WT0 + HF * HF)
#define WT2 (WT1 + HF * HF)
#define WCONV_B 576                            // WT2/256
#define PRO_B   (ENC_B + ADJ_B + BOFF_B + WCONV_B)

__global__ __launch_bounds__(256) void prologue_kernel(
        const float* __restrict__ sf, const float* __restrict__ bw,
        const float* __restrict__ bb, bf16* __restrict__ xenc,
        const int* __restrict__ esrc, const int* __restrict__ edst,
        int* __restrict__ deg, unsigned short* __restrict__ adj,
        const int* __restrict__ batch, int* __restrict__ boff,
        const float* __restrict__ w0, const float* __restrict__ w1,
        const float* __restrict__ w2, bf16* __restrict__ wT) {
    int b = blockIdx.x, t = threadIdx.x;
    if (b < ENC_B) {
        // encoder: x0 = relu(sf @ bbox_w + bbox_b) -> bf16
        int i = b * 256 + t;
        int n = i >> 6, f = i & 63;
        float acc = bb[f];
#pragma unroll
        for (int k = 0; k < 5; ++k)
            acc += sf[n * 5 + k] * bw[k * FDIM + f];
        xenc[i] = __float2bfloat16(fmaxf(acc, 0.f));
    } else if (b < ENC_B + ADJ_B) {
        // adjacency build: deg histogram + padded bucket fill
        int e = (b - ENC_B) * 256 + t;
        if (e >= E2) return;
        int s, d;
        if (e < N_EDGES) { s = esrc[e]; d = edst[e]; }
        else             { s = d = e - N_EDGES; }      // self-loop
        int pos = atomicAdd(&deg[d], 1);
        if (pos < DEGCAP) adj[d * DEGCAP + pos] = (unsigned short)s;
    } else if (b < ENC_B + ADJ_B + BOFF_B) {
        // batch offsets: batch[] is sorted -> segment == contiguous range
        int n = (b - ENC_B - ADJ_B) * 256 + t;
        if (n >= N_NODES) return;
        int b1 = batch[n];
        int b0 = (n == 0) ? -1 : batch[n - 1];
        for (int x = b0 + 1; x <= b1; ++x) boff[x] = n;
        if (n == N_NODES - 1)
            for (int x = b1 + 1; x <= NB; ++x) boff[x] = N_NODES;
    } else {
        // weight prep: wT[n][k] = bf16(w[k][n]), 3 layers packed
        int i = (b - ENC_B - ADJ_B - BOFF_B) * 256 + t;
        if (i < WT0) {
            int n = i / FDIM, k = i - n * FDIM;
            wT[i] = __float2bfloat16(w0[k * HF + n]);
        } else if (i < WT1) {
            int j = i - WT0, n = j >> 8, k = j & 255;
            wT[i] = __float2bfloat16(w1[k * HF + n]);
        } else if (i < WT2) {
            int j = i - WT1, n = j >> 8, k = j & 255;
            wT[i] = __float2bfloat16(w2[k * HF + n]);
        }
    }
}

// ---- 2. MFMA GEMM v3: 32-row M-tile, 256-thread blocks, grid 938.
//      R11 post-mortem: R9 (469 blk) and R10 (1876x1-wave) both = 7.3 waves/CU
//      -> latency-bound at <2 waves/SIMD. Halving M doubles wave count
//      (14.7 waves/CU) with B-restage cost absorbed by L2. Wave w = head. ----
template <int K>
__global__ __launch_bounds__(256) void gemm_mfma_kernel(
        const bf16* __restrict__ xb, const bf16* __restrict__ wT,
        bf16* __restrict__ y, const float* __restrict__ asrc,
        const float* __restrict__ adst, float* __restrict__ a_s,
        float* __restrict__ a_d) {
    __shared__ short sA[32 * LDA];      // A tile: 32 rows x 32 k
    __shared__ short sB[256 * LDA];     // B tile: 256 cols x 32 k (wT rows)
    int t = threadIdx.x, w = t >> 6, l = t & 63;
    int q = l >> 4, m = l & 15;
    int n0 = blockIdx.x * 32;
    const short* xg = (const short*)xb;
    const short* wg = (const short*)wT;
    int ar = t >> 2, ac = t & 3;        // A staging (threads 0..127): row, chunk
    f32x4 acc[2][4];
#pragma unroll
    for (int rt = 0; rt < 2; ++rt)
#pragma unroll
        for (int ct = 0; ct < 4; ++ct)
            acc[rt][ct] = (f32x4){0.f, 0.f, 0.f, 0.f};

    // initial tile -> registers
    short8 pa = {0, 0, 0, 0, 0, 0, 0, 0};
    short8 pb[4];
    if (t < 128 && n0 + ar < N_NODES)
        pa = *(const short8*)&xg[(long)(n0 + ar) * K + ac * 8];
#pragma unroll
    for (int u = 0; u < 4; ++u)
        pb[u] = *(const short8*)&wg[(long)t * K + u * 8];

#pragma unroll
    for (int k0 = 0; k0 < K; k0 += 32) {
        // commit staged regs to LDS
        if (t < 128) *(short8*)&sA[ar * LDA + ac * 8] = pa;
        {
            short* dst = &sB[t * LDA];
#pragma unroll
            for (int u = 0; u < 4; ++u) *(short8*)&dst[u * 8] = pb[u];
        }
        __syncthreads();
        // prefetch next tile while MFMA runs
        if (k0 + 32 < K) {
            pa = (short8){0, 0, 0, 0, 0, 0, 0, 0};
            if (t < 128 && n0 + ar < N_NODES)
                pa = *(const short8*)&xg[(long)(n0 + ar) * K + k0 + 32 + ac * 8];
#pragma unroll
            for (int u = 0; u < 4; ++u)
                pb[u] = *(const short8*)&wg[(long)t * K + k0 + 32 + u * 8];
        }
        // fragments: A[m=lane&15][k=quad*8+j], B[k=quad*8+j][n=lane&15]
        short8 af[2], bfr[4];
#pragma unroll
        for (int rt = 0; rt < 2; ++rt)
            af[rt] = *(const short8*)&sA[(16 * rt + m) * LDA + q * 8];
#pragma unroll
        for (int ct = 0; ct < 4; ++ct)
            bfr[ct] = *(const short8*)&sB[(64 * w + 16 * ct + m) * LDA + q * 8];
#pragma unroll
        for (int rt = 0; rt < 2; ++rt)
#pragma unroll
            for (int ct = 0; ct < 4; ++ct)
                acc[rt][ct] = __builtin_amdgcn_mfma_f32_16x16x32_bf16(
                    af[rt], bfr[ct], acc[rt][ct], 0, 0, 0);
        __syncthreads();
    }

    // epilogue A: store xs bf16 (C/D layout: col=lane&15, row=quad*4+reg)
#pragma unroll
    for (int rt = 0; rt < 2; ++rt)
#pragma unroll
        for (int reg = 0; reg < 4; ++reg) {
            int row = n0 + 16 * rt + 4 * q + reg;
            if (row < N_NODES) {
#pragma unroll
                for (int ct = 0; ct < 4; ++ct)
                    y[(long)row * HF + 64 * w + 16 * ct + m] =
                        __float2bfloat16(acc[rt][ct][reg]);
            }
        }
    // epilogue B: attention scalars (fp32 accumulators). head h == w.
    float vs[4], vd[4];
#pragma unroll
    for (int ct = 0; ct < 4; ++ct) {
        vs[ct] = asrc[64 * w + 16 * ct + m];
        vd[ct] = adst[64 * w + 16 * ct + m];
    }
#pragma unroll
    for (int rt = 0; rt < 2; ++rt)
#pragma unroll
        for (int reg = 0; reg < 4; ++reg) {
            float ps = 0.f, pd = 0.f;
#pragma unroll
            for (int ct = 0; ct < 4; ++ct) {
                ps += acc[rt][ct][reg] * vs[ct];
                pd += acc[rt][ct][reg] * vd[ct];
            }
#pragma unroll
            for (int mask = 1; mask <= 8; mask <<= 1) {
                ps += __shfl_xor(ps, mask, 64);
                pd += __shfl_xor(pd, mask, 64);
            }
            if (m == 0) {
                int row = n0 + 16 * rt + 4 * q + reg;
                if (row < N_NODES) {
                    a_s[row * NH + w] = ps;
                    a_d[row * NH + w] = pd;
                }
            }
        }
}

// ---- 3. fused per-dst aggregation — R6 structure (measured 44 us/layer, 4x).
//         RULE (R4, R8): do NOT restructure phase 2. thread = channel, block
//         streams whole 512B rows; 8-deep unroll; scalar bf16 gather. ----
__global__ __launch_bounds__(256) void agg_kernel(
        const unsigned short* __restrict__ adj, const int* __restrict__ deg,
        const bf16* __restrict__ xs, const float* __restrict__ a_s,
        const float* __restrict__ a_d, const float* __restrict__ bias,
        bf16* __restrict__ xout) {
    int n = blockIdx.x;                        // one block per dst node
    int t = threadIdx.x;                       // 256 threads; wave = head in phase 1
    int h = t >> 6, j = t & 63;
    __shared__ unsigned short s_src[DEGCAP];
    __shared__ float s_ex[NH * DEGCAP];
    __shared__ float s_rden[NH];
    int dn = min(deg[n], DEGCAP);
    if (t < DEGCAP) s_src[t] = (t < dn) ? adj[n * DEGCAP + t] : (unsigned short)0;
    __syncthreads();
    // phase 1: per-edge softmax numerators + per-head denominator.
    // segment_max subtraction skipped: logits are O(0.1) (softmax shift-invariant,
    // 1e-16 epsilon negligible either way) -> exp never overflows.
    float adh = a_d[n * NH + h];
    float ex = 0.f;
    if (j < dn) {
        int src = s_src[j];
        float a = a_s[src * NH + h] + adh;
        a = (a > 0.f) ? a : 0.2f * a;          // leaky_relu(0.2)
        ex = __expf(a);
    }
    s_ex[t] = ex;                              // t == h*DEGCAP + j; 0 pad for j>=dn
    float sum = ex;
#pragma unroll
    for (int off = 32; off > 0; off >>= 1) sum += __shfl_down(sum, off, 64);
    if (j == 0) s_rden[h] = 1.f / (sum + 1e-16f);
    __syncthreads();
    // phase 1.5: prenormalize alphas (one mul/thread vs dn8/thread in the loop)
    s_ex[t] *= s_rden[t >> 6];
    __syncthreads();
    // phase 2: t = output channel; 8-deep unrolled gather (pad slots: alpha=0)
    float acc = 0.f;
    int dn8 = (dn + 7) & ~7;
    for (int k = 0; k < dn8; k += 8) {
        int s0 = s_src[k],     s1 = s_src[k + 1], s2 = s_src[k + 2], s3 = s_src[k + 3];
        int s4 = s_src[k + 4], s5 = s_src[k + 5], s6 = s_src[k + 6], s7 = s_src[k + 7];
        float a0 = s_ex[h * DEGCAP + k];
        float a1 = s_ex[h * DEGCAP + k + 1];
        float a2 = s_ex[h * DEGCAP + k + 2];
        float a3 = s_ex[h * DEGCAP + k + 3];
        float a4 = s_ex[h * DEGCAP + k + 4];
        float a5 = s_ex[h * DEGCAP + k + 5];
        float a6 = s_ex[h * DEGCAP + k + 6];
        float a7 = s_ex[h * DEGCAP + k + 7];
        float v0 = b2f(xs[(long)s0 * HF + t]);
        float v1 = b2f(xs[(long)s1 * HF + t]);
        float v2 = b2f(xs[(long)s2 * HF + t]);
        float v3 = b2f(xs[(long)s3 * HF + t]);
        float v4 = b2f(xs[(long)s4 * HF + t]);
        float v5 = b2f(xs[(long)s5 * HF + t]);
        float v6 = b2f(xs[(long)s6 * HF + t]);
        float v7 = b2f(xs[(long)s7 * HF + t]);
        acc += a0 * v0; acc += a1 * v1; acc += a2 * v2; acc += a3 * v3;
        acc += a4 * v4; acc += a5 * v5; acc += a6 * v6; acc += a7 * v7;
    }
    xout[(long)n * HF + t] = __float2bfloat16(fmaxf(acc + bias[t], 0.f));
}

// ---- 3b. range max-pool over sorted batch, PSPLIT blocks per batch.
//          bf16 rounding is monotone: max(round(x)) == round(max(x));
//          values >= 0 (post-relu) -> uint atomicMax on 0-init g is exact. ----
__global__ __launch_bounds__(256) void pool256_kernel(const bf16* __restrict__ x,
                                                      const int* __restrict__ boff,
                                                      unsigned int* __restrict__ g, int goff) {
    int b = blockIdx.x / PSPLIT, part = blockIdx.x % PSPLIT;
    int t = threadIdx.x;                       // thread = column
    int s = boff[b], e = boff[b + 1];
    int chunk = (e - s + PSPLIT - 1) / PSPLIT;
    int cs = s + part * chunk, ce = min(cs + chunk, e);
    if (cs >= ce) return;
    float v0 = 0.f, v1 = 0.f;
    int n = cs;
    for (; n + 1 < ce; n += 2) {
        v0 = fmaxf(v0, b2f(x[(long)n * HF + t]));
        v1 = fmaxf(v1, b2f(x[(long)(n + 1) * HF + t]));
    }
    if (n < ce) v0 = fmaxf(v0, b2f(x[(long)n * HF + t]));
    atomicMax(&g[b * GCOLS + goff + t], __float_as_uint(fmaxf(v0, v1)));
}

__global__ __launch_bounds__(256) void pool64_kernel(const bf16* __restrict__ x,
                                                     const int* __restrict__ boff,
                                                     unsigned int* __restrict__ g) {
    int b = blockIdx.x / PSPLIT, part = blockIdx.x % PSPLIT;
    int t = threadIdx.x, c = t & 63, r = t >> 6;   // 4 rows in flight
    int s = boff[b], e = boff[b + 1];
    int chunk = (e - s + PSPLIT - 1) / PSPLIT;
    int cs = s + part * chunk, ce = min(cs + chunk, e);
    __shared__ float sm[256];
    float v = 0.f;
    for (int n = cs + r; n < ce; n += 4)
        v = fmaxf(v, b2f(x[(long)n * FDIM + c]));
    sm[t] = v;
    __syncthreads();
    if (t < 64 && cs < ce) {
        float m = fmaxf(fmaxf(sm[t], sm[t + 64]), fmaxf(sm[t + 128], sm[t + 192]));
        atomicMax(&g[b * GCOLS + t], __float_as_uint(m));
    }
}

// ---- 4. head: d_out = g_embed @ agg_w + agg_b, split-K over FSPLIT slices.
//          d_out memset to 0 first; fp32 atomicAdd accumulation. ----
__global__ __launch_bounds__(256) void final_kernel(
        const float* __restrict__ g, const float* __restrict__ w,
        const float* __restrict__ b, float* __restrict__ outp) {
    int bb = blockIdx.x & (NB - 1);
    int slice = blockIdx.x >> 6;               // 0..FSPLIT-1
    int j = threadIdx.x;                       // output column
    const int KS = GCOLS / FSPLIT;             // 104
    float acc = (slice == 0) ? b[j] : 0.f;
    int k0 = slice * KS;
    for (int k = k0; k < k0 + KS; ++k)
        acc += g[bb * GCOLS + k] * w[k * BOTD + j];
    atomicAdd(&outp[bb * BOTD + j], acc);
}

extern "C" void kernel_launch(void* const* d_in, const int* in_sizes, int n_in,
                              void* d_out, int out_size, void* d_ws, size_t ws_size,
                              hipStream_t stream) {
    const float* sf     = (const float*)d_in[0];
    const int*   eidx   = (const int*)d_in[1];
    const int*   batch  = (const int*)d_in[2];
    const float* bbox_w = (const float*)d_in[3];
    const float* bbox_b = (const float*)d_in[4];
    const float* lin_w[3] = {(const float*)d_in[5],  (const float*)d_in[9],  (const float*)d_in[13]};
    const float* att_s[3] = {(const float*)d_in[6],  (const float*)d_in[10], (const float*)d_in[14]};
    const float* att_d[3] = {(const float*)d_in[7],  (const float*)d_in[11], (const float*)d_in[15]};
    const float* bias[3]  = {(const float*)d_in[8],  (const float*)d_in[12], (const float*)d_in[16]};
    const float* agg_w  = (const float*)d_in[17];
    const float* agg_b  = (const float*)d_in[18];

    const int* esrc = eidx;               // edge_index[0]
    const int* edst = eidx + N_EDGES;     // edge_index[1]

    // Workspace carve-up (~55 MB):
    char* ws = (char*)d_ws;
    bf16* xsb  = (bf16*)ws;  ws += (size_t)N_NODES * HF * 2;       // gemm out (scratch/layer)
    bf16* xb0  = (bf16*)ws;  ws += (size_t)N_NODES * HF * 2;       // layer-out ping
    bf16* xb1  = (bf16*)ws;  ws += (size_t)N_NODES * HF * 2;       // layer-out pong
    bf16* xenc = (bf16*)ws;  ws += (size_t)N_NODES * FDIM * 2;     // encoder out
    float* a_s = (float*)ws; ws += (size_t)N_NODES * NH * 4;
    float* a_d = (float*)ws; ws += (size_t)N_NODES * NH * 4;
    float* g   = (float*)ws; ws += (size_t)NB * GCOLS * 4;         // 0-init, atomicMax'd
    int*   deg = (int*)ws;   ws += (size_t)N_NODES * 4;
    int*   boff= (int*)ws;   ws += (size_t)(NB + 1) * 4;
    unsigned short* adj = (unsigned short*)ws; ws += (size_t)N_NODES * DEGCAP * 2;
    bf16* wT   = (bf16*)ws;  ws += (size_t)WT2 * 2;                // all 3 layers

    hipMemsetAsync(deg, 0, (size_t)N_NODES * 4, stream);
    hipMemsetAsync(g, 0, (size_t)NB * GCOLS * 4, stream);
    hipMemsetAsync(d_out, 0, (size_t)NB * BOTD * 4, stream);
    prologue_kernel<<<PRO_B, 256, 0, stream>>>(
        sf, bbox_w, bbox_b, xenc, esrc, edst, deg, adj, batch, boff,
        lin_w[0], lin_w[1], lin_w[2], wT);
    pool64_kernel<<<NB * PSPLIT, 256, 0, stream>>>(xenc, boff, (unsigned int*)g);

    const bf16* wTl[3] = {wT, wT + WT0, wT + WT1};
    const bf16* xin = xenc;
    bf16* xout = xb0;
    int ggrid = (N_NODES + 31) / 32;           // 938 blocks, 14.7 waves/CU
    for (int l = 0; l < 3; ++l) {
        if (l == 0)
            gemm_mfma_kernel<FDIM><<<ggrid, 256, 0, stream>>>(
                xin, wTl[l], xsb, att_s[l], att_d[l], a_s, a_d);
        else
            gemm_mfma_kernel<HF><<<ggrid, 256, 0, stream>>>(
                xin, wTl[l], xsb, att_s[l], att_d[l], a_s, a_d);
        agg_kernel<<<N_NODES, 256, 0, stream>>>(adj, deg, xsb, a_s, a_d, bias[l], xout);
        pool256_kernel<<<NB * PSPLIT, 256, 0, stream>>>(xout, boff, (unsigned int*)g, FDIM + l * HF);
        xin = xout;
        xout = (xout == xb0) ? xb1 : xb0;
    }
    final_kernel<<<NB * FSPLIT, 256, 0, stream>>>(g, agg_w, agg_b, (float*)d_out);
}

// Round 13
// 334.567 us; speedup vs baseline: 1.0585x; 1.0585x over previous
//
#include <hip/hip_runtime.h>
#include <hip/hip_bf16.h>

// Problem constants (fixed by the reference).
#define N_NODES 30000
#define N_EDGES 240000
#define NB      64                  // batches
#define FDIM    64                  // F
#define NH      4                   // heads
#define HF      256                 // H*F
#define E2      (N_EDGES + N_NODES) // edges + self-loops
#define GCOLS   832                 // F*(1+H*T)
#define BOTD    256
#define DEGCAP  64                  // max in-degree bucket (Poisson(9): P(>63) ~ 1e-30)
#define PSPLIT  16                  // pool parallelism: blocks per batch
#define FSPLIT  8                   // final head split-K (832 = 8*104)

typedef __hip_bfloat16 bf16;
typedef __attribute__((ext_vector_type(8))) short short8;
typedef __attribute__((ext_vector_type(4))) float f32x4;

#define LDA 40   // LDS stride in halves: 80B = 16B-aligned, 2-way banking (free)

__device__ __forceinline__ float b2f(bf16 v) { return __bfloat162float(v); }

// ---- 0. mega-prologue: six independent jobs in one dispatch.
//      sections: [enc | fill_adj | boff | wconv | zero-g | zero-dout].
//      branch is block-uniform. g/d_out consumers all run after this kernel. ----
#define ENC_B   7500                           // N*64/256
#define ADJ_B   1055                           // ceil(E2/256)
#define BOFF_B  118                            // ceil(N/256)
#define WT0 (HF * FDIM)
#define WT1 (WT0 + HF * HF)
#define WT2 (WT1 + HF * HF)
#define WCONV_B 576                            // WT2/256
#define GZ_B    208                            // NB*GCOLS/256
#define OZ_B    64                             // NB*BOTD/256
#define PRO_B   (ENC_B + ADJ_B + BOFF_B + WCONV_B + GZ_B + OZ_B)

__global__ __launch_bounds__(256) void prologue_kernel(
        const float* __restrict__ sf, const float* __restrict__ bw,
        const float* __restrict__ bb, bf16* __restrict__ xenc,
        const int* __restrict__ esrc, const int* __restrict__ edst,
        int* __restrict__ deg, unsigned short* __restrict__ adj,
        const int* __restrict__ batch, int* __restrict__ boff,
        const float* __restrict__ w0, const float* __restrict__ w1,
        const float* __restrict__ w2, bf16* __restrict__ wT,
        float* __restrict__ g, float* __restrict__ dout) {
    int b = blockIdx.x, t = threadIdx.x;
    if (b < ENC_B) {
        // encoder: x0 = relu(sf @ bbox_w + bbox_b) -> bf16
        int i = b * 256 + t;
        int n = i >> 6, f = i & 63;
        float acc = bb[f];
#pragma unroll
        for (int k = 0; k < 5; ++k)
            acc += sf[n * 5 + k] * bw[k * FDIM + f];
        xenc[i] = __float2bfloat16(fmaxf(acc, 0.f));
    } else if (b < ENC_B + ADJ_B) {
        // adjacency build: deg histogram + padded bucket fill
        int e = (b - ENC_B) * 256 + t;
        if (e >= E2) return;
        int s, d;
        if (e < N_EDGES) { s = esrc[e]; d = edst[e]; }
        else             { s = d = e - N_EDGES; }      // self-loop
        int pos = atomicAdd(&deg[d], 1);
        if (pos < DEGCAP) adj[d * DEGCAP + pos] = (unsigned short)s;
    } else if (b < ENC_B + ADJ_B + BOFF_B) {
        // batch offsets: batch[] is sorted -> segment == contiguous range
        int n = (b - ENC_B - ADJ_B) * 256 + t;
        if (n >= N_NODES) return;
        int b1 = batch[n];
        int b0 = (n == 0) ? -1 : batch[n - 1];
        for (int x = b0 + 1; x <= b1; ++x) boff[x] = n;
        if (n == N_NODES - 1)
            for (int x = b1 + 1; x <= NB; ++x) boff[x] = N_NODES;
    } else if (b < ENC_B + ADJ_B + BOFF_B + WCONV_B) {
        // weight prep: wT[n][k] = bf16(w[k][n]), 3 layers packed
        int i = (b - ENC_B - ADJ_B - BOFF_B) * 256 + t;
        if (i < WT0) {
            int n = i / FDIM, k = i - n * FDIM;
            wT[i] = __float2bfloat16(w0[k * HF + n]);
        } else if (i < WT1) {
            int j = i - WT0, n = j >> 8, k = j & 255;
            wT[i] = __float2bfloat16(w1[k * HF + n]);
        } else if (i < WT2) {
            int j = i - WT1, n = j >> 8, k = j & 255;
            wT[i] = __float2bfloat16(w2[k * HF + n]);
        }
    } else if (b < ENC_B + ADJ_B + BOFF_B + WCONV_B + GZ_B) {
        // zero g (pool atomicMax target; consumed by pool64 after this kernel)
        g[(b - ENC_B - ADJ_B - BOFF_B - WCONV_B) * 256 + t] = 0.f;
    } else {
        // zero d_out (final_kernel atomicAdd target)
        dout[(b - ENC_B - ADJ_B - BOFF_B - WCONV_B - GZ_B) * 256 + t] = 0.f;
    }
}

// ---- 2. MFMA GEMM (R10 config — best measured: 64-row tile, 469x256t).
//      R11 (1-wave blocks) and R12 (32-row) both regressed; variants are
//      noise-bound at ~±4%. K template -> unrolled; register-prefetch dbuf. ----
template <int K>
__global__ __launch_bounds__(256) void gemm_mfma_kernel(
        const bf16* __restrict__ xb, const bf16* __restrict__ wT,
        bf16* __restrict__ y, const float* __restrict__ asrc,
        const float* __restrict__ adst, float* __restrict__ a_s,
        float* __restrict__ a_d) {
    __shared__ short sA[64 * LDA];      // A tile: 64 rows x 32 k
    __shared__ short sB[256 * LDA];     // B tile: 256 cols x 32 k (wT rows)
    int t = threadIdx.x, w = t >> 6, l = t & 63;
    int q = l >> 4, m = l & 15;
    int n0 = blockIdx.x * 64;
    const short* xg = (const short*)xb;
    const short* wg = (const short*)wT;
    int ar = t >> 2, ac = t & 3;        // A staging: row, 8-half chunk
    f32x4 acc[4][4];
#pragma unroll
    for (int rt = 0; rt < 4; ++rt)
#pragma unroll
        for (int ct = 0; ct < 4; ++ct)
            acc[rt][ct] = (f32x4){0.f, 0.f, 0.f, 0.f};

    // initial tile -> registers
    short8 pa = {0, 0, 0, 0, 0, 0, 0, 0};
    short8 pb[4];
    if (n0 + ar < N_NODES) pa = *(const short8*)&xg[(long)(n0 + ar) * K + ac * 8];
#pragma unroll
    for (int u = 0; u < 4; ++u)
        pb[u] = *(const short8*)&wg[(long)t * K + u * 8];

#pragma unroll
    for (int k0 = 0; k0 < K; k0 += 32) {
        // commit staged regs to LDS
        *(short8*)&sA[ar * LDA + ac * 8] = pa;
        {
            short* dst = &sB[t * LDA];
#pragma unroll
            for (int u = 0; u < 4; ++u) *(short8*)&dst[u * 8] = pb[u];
        }
        __syncthreads();
        // prefetch next tile while MFMA runs
        if (k0 + 32 < K) {
            pa = (short8){0, 0, 0, 0, 0, 0, 0, 0};
            if (n0 + ar < N_NODES)
                pa = *(const short8*)&xg[(long)(n0 + ar) * K + k0 + 32 + ac * 8];
#pragma unroll
            for (int u = 0; u < 4; ++u)
                pb[u] = *(const short8*)&wg[(long)t * K + k0 + 32 + u * 8];
        }
        // fragments: A[m=lane&15][k=quad*8+j], B[k=quad*8+j][n=lane&15]
        short8 af[4], bfr[4];
#pragma unroll
        for (int rt = 0; rt < 4; ++rt)
            af[rt] = *(const short8*)&sA[(16 * rt + m) * LDA + q * 8];
#pragma unroll
        for (int ct = 0; ct < 4; ++ct)
            bfr[ct] = *(const short8*)&sB[(64 * w + 16 * ct + m) * LDA + q * 8];
#pragma unroll
        for (int rt = 0; rt < 4; ++rt)
#pragma unroll
            for (int ct = 0; ct < 4; ++ct)
                acc[rt][ct] = __builtin_amdgcn_mfma_f32_16x16x32_bf16(
                    af[rt], bfr[ct], acc[rt][ct], 0, 0, 0);
        __syncthreads();
    }

    // epilogue A: store xs bf16 (C/D layout: col=lane&15, row=quad*4+reg)
#pragma unroll
    for (int rt = 0; rt < 4; ++rt)
#pragma unroll
        for (int reg = 0; reg < 4; ++reg) {
            int row = n0 + 16 * rt + 4 * q + reg;
            if (row < N_NODES) {
#pragma unroll
                for (int ct = 0; ct < 4; ++ct)
                    y[(long)row * HF + 64 * w + 16 * ct + m] =
                        __float2bfloat16(acc[rt][ct][reg]);
            }
        }
    // epilogue B: attention scalars (fp32 accumulators). head h == w.
    float vs[4], vd[4];
#pragma unroll
    for (int ct = 0; ct < 4; ++ct) {
        vs[ct] = asrc[64 * w + 16 * ct + m];
        vd[ct] = adst[64 * w + 16 * ct + m];
    }
#pragma unroll
    for (int rt = 0; rt < 4; ++rt)
#pragma unroll
        for (int reg = 0; reg < 4; ++reg) {
            float ps = 0.f, pd = 0.f;
#pragma unroll
            for (int ct = 0; ct < 4; ++ct) {
                ps += acc[rt][ct][reg] * vs[ct];
                pd += acc[rt][ct][reg] * vd[ct];
            }
#pragma unroll
            for (int mask = 1; mask <= 8; mask <<= 1) {
                ps += __shfl_xor(ps, mask, 64);
                pd += __shfl_xor(pd, mask, 64);
            }
            if (m == 0) {
                int row = n0 + 16 * rt + 4 * q + reg;
                if (row < N_NODES) {
                    a_s[row * NH + w] = ps;
                    a_d[row * NH + w] = pd;
                }
            }
        }
}

// ---- 3. fused per-dst aggregation — R6 structure (measured 44 us/layer, 5x).
//         RULE (R4, R8): do NOT restructure phase 2. thread = channel, block
//         streams whole 512B rows; 8-deep unroll; scalar bf16 gather. ----
__global__ __launch_bounds__(256) void agg_kernel(
        const unsigned short* __restrict__ adj, const int* __restrict__ deg,
        const bf16* __restrict__ xs, const float* __restrict__ a_s,
        const float* __restrict__ a_d, const float* __restrict__ bias,
        bf16* __restrict__ xout) {
    int n = blockIdx.x;                        // one block per dst node
    int t = threadIdx.x;                       // 256 threads; wave = head in phase 1
    int h = t >> 6, j = t & 63;
    __shared__ unsigned short s_src[DEGCAP];
    __shared__ float s_ex[NH * DEGCAP];
    __shared__ float s_rden[NH];
    int dn = min(deg[n], DEGCAP);
    if (t < DEGCAP) s_src[t] = (t < dn) ? adj[n * DEGCAP + t] : (unsigned short)0;
    __syncthreads();
    // phase 1: per-edge softmax numerators + per-head denominator.
    // segment_max subtraction skipped: logits are O(0.1) (softmax shift-invariant,
    // 1e-16 epsilon negligible either way) -> exp never overflows.
    float adh = a_d[n * NH + h];
    float ex = 0.f;
    if (j < dn) {
        int src = s_src[j];
        float a = a_s[src * NH + h] + adh;
        a = (a > 0.f) ? a : 0.2f * a;          // leaky_relu(0.2)
        ex = __expf(a);
    }
    s_ex[t] = ex;                              // t == h*DEGCAP + j; 0 pad for j>=dn
    float sum = ex;
#pragma unroll
    for (int off = 32; off > 0; off >>= 1) sum += __shfl_down(sum, off, 64);
    if (j == 0) s_rden[h] = 1.f / (sum + 1e-16f);
    __syncthreads();
    // phase 1.5: prenormalize alphas (one mul/thread vs dn8/thread in the loop)
    s_ex[t] *= s_rden[t >> 6];
    __syncthreads();
    // phase 2: t = output channel; 8-deep unrolled gather (pad slots: alpha=0)
    float acc = 0.f;
    int dn8 = (dn + 7) & ~7;
    for (int k = 0; k < dn8; k += 8) {
        int s0 = s_src[k],     s1 = s_src[k + 1], s2 = s_src[k + 2], s3 = s_src[k + 3];
        int s4 = s_src[k + 4], s5 = s_src[k + 5], s6 = s_src[k + 6], s7 = s_src[k + 7];
        float a0 = s_ex[h * DEGCAP + k];
        float a1 = s_ex[h * DEGCAP + k + 1];
        float a2 = s_ex[h * DEGCAP + k + 2];
        float a3 = s_ex[h * DEGCAP + k + 3];
        float a4 = s_ex[h * DEGCAP + k + 4];
        float a5 = s_ex[h * DEGCAP + k + 5];
        float a6 = s_ex[h * DEGCAP + k + 6];
        float a7 = s_ex[h * DEGCAP + k + 7];
        float v0 = b2f(xs[(long)s0 * HF + t]);
        float v1 = b2f(xs[(long)s1 * HF + t]);
        float v2 = b2f(xs[(long)s2 * HF + t]);
        float v3 = b2f(xs[(long)s3 * HF + t]);
        float v4 = b2f(xs[(long)s4 * HF + t]);
        float v5 = b2f(xs[(long)s5 * HF + t]);
        float v6 = b2f(xs[(long)s6 * HF + t]);
        float v7 = b2f(xs[(long)s7 * HF + t]);
        acc += a0 * v0; acc += a1 * v1; acc += a2 * v2; acc += a3 * v3;
        acc += a4 * v4; acc += a5 * v5; acc += a6 * v6; acc += a7 * v7;
    }
    xout[(long)n * HF + t] = __float2bfloat16(fmaxf(acc + bias[t], 0.f));
}

// ---- 3b. range max-pool over sorted batch, PSPLIT blocks per batch.
//          bf16 rounding is monotone: max(round(x)) == round(max(x));
//          values >= 0 (post-relu) -> uint atomicMax on 0-init g is exact. ----
__global__ __launch_bounds__(256) void pool256_kernel(const bf16* __restrict__ x,
                                                      const int* __restrict__ boff,
                                                      unsigned int* __restrict__ g, int goff) {
    int b = blockIdx.x / PSPLIT, part = blockIdx.x % PSPLIT;
    int t = threadIdx.x;                       // thread = column
    int s = boff[b], e = boff[b + 1];
    int chunk = (e - s + PSPLIT - 1) / PSPLIT;
    int cs = s + part * chunk, ce = min(cs + chunk, e);
    if (cs >= ce) return;
    float v0 = 0.f, v1 = 0.f;
    int n = cs;
    for (; n + 1 < ce; n += 2) {
        v0 = fmaxf(v0, b2f(x[(long)n * HF + t]));
        v1 = fmaxf(v1, b2f(x[(long)(n + 1) * HF + t]));
    }
    if (n < ce) v0 = fmaxf(v0, b2f(x[(long)n * HF + t]));
    atomicMax(&g[b * GCOLS + goff + t], __float_as_uint(fmaxf(v0, v1)));
}

__global__ __launch_bounds__(256) void pool64_kernel(const bf16* __restrict__ x,
                                                     const int* __restrict__ boff,
                                                     unsigned int* __restrict__ g) {
    int b = blockIdx.x / PSPLIT, part = blockIdx.x % PSPLIT;
    int t = threadIdx.x, c = t & 63, r = t >> 6;   // 4 rows in flight
    int s = boff[b], e = boff[b + 1];
    int chunk = (e - s + PSPLIT - 1) / PSPLIT;
    int cs = s + part * chunk, ce = min(cs + chunk, e);
    __shared__ float sm[256];
    float v = 0.f;
    for (int n = cs + r; n < ce; n += 4)
        v = fmaxf(v, b2f(x[(long)n * FDIM + c]));
    sm[t] = v;
    __syncthreads();
    if (t < 64 && cs < ce) {
        float m = fmaxf(fmaxf(sm[t], sm[t + 64]), fmaxf(sm[t + 128], sm[t + 192]));
        atomicMax(&g[b * GCOLS + t], __float_as_uint(m));
    }
}

// ---- 4. head: d_out = g_embed @ agg_w + agg_b, split-K over FSPLIT slices.
//          d_out zeroed in prologue; fp32 atomicAdd accumulation. ----
__global__ __launch_bounds__(256) void final_kernel(
        const float* __restrict__ g, const float* __restrict__ w,
        const float* __restrict__ b, float* __restrict__ outp) {
    int bb = blockIdx.x & (NB - 1);
    int slice = blockIdx.x >> 6;               // 0..FSPLIT-1
    int j = threadIdx.x;                       // output column
    const int KS = GCOLS / FSPLIT;             // 104
    float acc = (slice == 0) ? b[j] : 0.f;
    int k0 = slice * KS;
    for (int k = k0; k < k0 + KS; ++k)
        acc += g[bb * GCOLS + k] * w[k * BOTD + j];
    atomicAdd(&outp[bb * BOTD + j], acc);
}

extern "C" void kernel_launch(void* const* d_in, const int* in_sizes, int n_in,
                              void* d_out, int out_size, void* d_ws, size_t ws_size,
                              hipStream_t stream) {
    const float* sf     = (const float*)d_in[0];
    const int*   eidx   = (const int*)d_in[1];
    const int*   batch  = (const int*)d_in[2];
    const float* bbox_w = (const float*)d_in[3];
    const float* bbox_b = (const float*)d_in[4];
    const float* lin_w[3] = {(const float*)d_in[5],  (const float*)d_in[9],  (const float*)d_in[13]};
    const float* att_s[3] = {(const float*)d_in[6],  (const float*)d_in[10], (const float*)d_in[14]};
    const float* att_d[3] = {(const float*)d_in[7],  (const float*)d_in[11], (const float*)d_in[15]};
    const float* bias[3]  = {(const float*)d_in[8],  (const float*)d_in[12], (const float*)d_in[16]};
    const float* agg_w  = (const float*)d_in[17];
    const float* agg_b  = (const float*)d_in[18];

    const int* esrc = eidx;               // edge_index[0]
    const int* edst = eidx + N_EDGES;     // edge_index[1]

    // Workspace carve-up (~55 MB):
    char* ws = (char*)d_ws;
    bf16* xsb  = (bf16*)ws;  ws += (size_t)N_NODES * HF * 2;       // gemm out (scratch/layer)
    bf16* xb0  = (bf16*)ws;  ws += (size_t)N_NODES * HF * 2;       // layer-out ping
    bf16* xb1  = (bf16*)ws;  ws += (size_t)N_NODES * HF * 2;       // layer-out pong
    bf16* xenc = (bf16*)ws;  ws += (size_t)N_NODES * FDIM * 2;     // encoder out
    float* a_s = (float*)ws; ws += (size_t)N_NODES * NH * 4;
    float* a_d = (float*)ws; ws += (size_t)N_NODES * NH * 4;
    float* g   = (float*)ws; ws += (size_t)NB * GCOLS * 4;         // zeroed in prologue
    int*   deg = (int*)ws;   ws += (size_t)N_NODES * 4;
    int*   boff= (int*)ws;   ws += (size_t)(NB + 1) * 4;
    unsigned short* adj = (unsigned short*)ws; ws += (size_t)N_NODES * DEGCAP * 2;
    bf16* wT   = (bf16*)ws;  ws += (size_t)WT2 * 2;                // all 3 layers

    hipMemsetAsync(deg, 0, (size_t)N_NODES * 4, stream);   // must precede prologue atomics
    prologue_kernel<<<PRO_B, 256, 0, stream>>>(
        sf, bbox_w, bbox_b, xenc, esrc, edst, deg, adj, batch, boff,
        lin_w[0], lin_w[1], lin_w[2], wT, g, (float*)d_out);
    pool64_kernel<<<NB * PSPLIT, 256, 0, stream>>>(xenc, boff, (unsigned int*)g);

    const bf16* wTl[3] = {wT, wT + WT0, wT + WT1};
    const bf16* xin = xenc;
    bf16* xout = xb0;
    for (int l = 0; l < 3; ++l) {
        if (l == 0)
            gemm_mfma_kernel<FDIM><<<(N_NODES + 63) / 64, 256, 0, stream>>>(
                xin, wTl[l], xsb, att_s[l], att_d[l], a_s, a_d);
        else
            gemm_mfma_kernel<HF><<<(N_NODES + 63) / 64, 256, 0, stream>>>(
                xin, wTl[l], xsb, att_s[l], att_d[l], a_s, a_d);
        agg_kernel<<<N_NODES, 256, 0, stream>>>(adj, deg, xsb, a_s, a_d, bias[l], xout);
        pool256_kernel<<<NB * PSPLIT, 256, 0, stream>>>(xout, boff, (unsigned int*)g, FDIM + l * HF);
        xin = xout;
        xout = (xout == xb0) ? xb1 : xb0;
    }
    final_kernel<<<NB * FSPLIT, 256, 0, stream>>>(g, agg_w, agg_b, (float*)d_out);
}